// Round 4
// baseline (427.039 us; speedup 1.0000x reference)
//
#include <hip/hip_runtime.h>
#include <hip/hip_bf16.h>

// Problem constants
#define BB 8
#define NN 16384
#define MM 4096
#define C1 64
#define C2 256
#define K1 320            // C1 + C2
#define CO 256
#define MTOT (BB * NN)    // 131072

// Workspace layout (bytes)
#define STATS_OFF 0                 // 8*256 floats
#define FLAG_OFF  8192
#define W1B_OFF   16384             // bf16 256x320
#define W2B_OFF   180224            // bf16 256x256
#define F2T_OFF   327680            // bf16 [B,M,C2]
#define XT_OFF    (327680 + 16777216)              // bf16 [MTOT,320]
#define H2_OFF    (327680 + 16777216 + 83886080)   // bf16 [B,N,CO] (row-major over global m)

typedef short v8s __attribute__((ext_vector_type(8)));
typedef float v4f __attribute__((ext_vector_type(4)));

__device__ __forceinline__ float bf2f(unsigned short u) {
    unsigned v = ((unsigned)u) << 16;
    float f;
    __builtin_memcpy(&f, &v, 4);
    return f;
}
__device__ __forceinline__ unsigned short f2bf(float f) {
    unsigned u;
    __builtin_memcpy(&u, &f, 4);
    unsigned r = u + 0x7fffu + ((u >> 16) & 1u);  // RNE
    return (unsigned short)(r >> 16);
}
__device__ __forceinline__ void gload16(const unsigned short* g, unsigned short* l) {
    __builtin_amdgcn_global_load_lds((const __attribute__((address_space(1))) unsigned int*)g,
                                     (__attribute__((address_space(3))) unsigned int*)l, 16, 0, 0);
}

// ---------------- prep: zero stats, idx width flag, W1/W2 -> bf16 ----------
__global__ void k_prep(const void* idx_raw, int* flag64, float* stats,
                       const float* __restrict__ W1, unsigned short* __restrict__ W1b,
                       const float* __restrict__ W2, unsigned short* __restrict__ W2b) {
    int blk = blockIdx.x;
    int t = threadIdx.x;
    if (blk < 320) {
        int e = blk * 256 + t;
        W1b[e] = f2bf(W1[e]);
    } else if (blk < 576) {
        int e = (blk - 320) * 256 + t;
        W2b[e] = f2bf(W2[e]);
    } else {
        for (int i = t; i < 8 * 256; i += 256) stats[i] = 0.f;
        if (t == 0) {
            const int* a = (const int*)idx_raw;
            int all0 = 1;
            for (int j = 1; j < 64; j += 2) all0 &= (a[j] == 0);
            *flag64 = all0;  // 1 => idx int64
        }
    }
}

// ------- transpose f2 [B,C2,M] -> f2t bf16 [B,M,C2]; 64ch x 32m tiles ------
__global__ void k_tr_f2(const float* __restrict__ f2, unsigned short* __restrict__ f2t) {
    __shared__ float tile[64][33];
    int b = blockIdx.z;
    int c0 = blockIdx.y * 64;
    int m0 = blockIdx.x * 32;
    int t = threadIdx.x;
    int lm = t & 31, lc = t >> 5;
    const float* src = f2 + ((size_t)b * C2 + c0) * MM + m0;
#pragma unroll
    for (int j = 0; j < 8; ++j)
        tile[lc + 8 * j][lm] = src[(size_t)(lc + 8 * j) * MM + lm];
    __syncthreads();
    int m = t >> 3, c8 = (t & 7) * 8;
    unsigned short tmp[8];
#pragma unroll
    for (int k = 0; k < 8; ++k) tmp[k] = f2bf(tile[c8 + k][m]);
    uint4 v;
    v.x = (unsigned)tmp[0] | ((unsigned)tmp[1] << 16);
    v.y = (unsigned)tmp[2] | ((unsigned)tmp[3] << 16);
    v.z = (unsigned)tmp[4] | ((unsigned)tmp[5] << 16);
    v.w = (unsigned)tmp[6] | ((unsigned)tmp[7] << 16);
    *(uint4*)&f2t[((size_t)b * MM + m0 + m) * C2 + c0 + c8] = v;
}

// ------- transpose f1 [B,C1,N] -> xT[:,0:64] bf16; 64ch x 32n tiles --------
__global__ void k_tr_f1(const float* __restrict__ f1, unsigned short* __restrict__ xT) {
    __shared__ float tile[64][33];
    int b = blockIdx.z;
    int n0 = blockIdx.x * 32;
    int t = threadIdx.x;
    int lm = t & 31, lc = t >> 5;
    const float* src = f1 + ((size_t)b * C1) * NN + n0;
#pragma unroll
    for (int j = 0; j < 8; ++j)
        tile[lc + 8 * j][lm] = src[(size_t)(lc + 8 * j) * NN + lm];
    __syncthreads();
    int m = t >> 3, c8 = (t & 7) * 8;
    unsigned short tmp[8];
#pragma unroll
    for (int k = 0; k < 8; ++k) tmp[k] = f2bf(tile[c8 + k][m]);
    uint4 v;
    v.x = (unsigned)tmp[0] | ((unsigned)tmp[1] << 16);
    v.y = (unsigned)tmp[2] | ((unsigned)tmp[3] << 16);
    v.z = (unsigned)tmp[4] | ((unsigned)tmp[5] << 16);
    v.w = (unsigned)tmp[6] | ((unsigned)tmp[7] << 16);
    *(uint4*)&xT[((size_t)b * NN + n0 + m) * K1 + c8] = v;
}

// ---------------- 3-NN inverse-distance interpolation -> xT[:,64:320] -------
__global__ void k_interp(const float* __restrict__ p1, const float* __restrict__ p2,
                         const void* __restrict__ idxv, const int* __restrict__ flag64,
                         const unsigned short* __restrict__ f2t,
                         unsigned short* __restrict__ xT) {
    int t = threadIdx.x;
    int p = t >> 5, lane = t & 31;
    size_t pt = (size_t)blockIdx.x * 8 + p;
    int b = (int)(pt >> 14);
    int m0, m1, m2;
    if (*flag64) {
        const long long* id = (const long long*)idxv;
        m0 = (int)id[pt * 3 + 0]; m1 = (int)id[pt * 3 + 1]; m2 = (int)id[pt * 3 + 2];
    } else {
        const int* id = (const int*)idxv;
        m0 = id[pt * 3 + 0]; m1 = id[pt * 3 + 1]; m2 = id[pt * 3 + 2];
    }
    float qx = p1[pt * 3 + 0], qy = p1[pt * 3 + 1], qz = p1[pt * 3 + 2];
    const float* pb = p2 + (size_t)b * MM * 3;
    float dx, dy, dz;
    dx = qx - pb[m0 * 3 + 0]; dy = qy - pb[m0 * 3 + 1]; dz = qz - pb[m0 * 3 + 2];
    float d0 = dx * dx + dy * dy + dz * dz;
    dx = qx - pb[m1 * 3 + 0]; dy = qy - pb[m1 * 3 + 1]; dz = qz - pb[m1 * 3 + 2];
    float d1 = dx * dx + dy * dy + dz * dz;
    dx = qx - pb[m2 * 3 + 0]; dy = qy - pb[m2 * 3 + 1]; dz = qz - pb[m2 * 3 + 2];
    float d2v = dx * dx + dy * dy + dz * dz;
    float r0 = 1.f / (d0 + 1e-8f), r1 = 1.f / (d1 + 1e-8f), r2 = 1.f / (d2v + 1e-8f);
    float inv = 1.f / (r0 + r1 + r2);
    float w0 = r0 * inv, w1 = r1 * inv, w2 = r2 * inv;

    const unsigned short* fb = f2t + (size_t)b * MM * C2;
    int c0 = lane * 8;
    uint4 va = *(const uint4*)(fb + (size_t)m0 * C2 + c0);
    uint4 vb = *(const uint4*)(fb + (size_t)m1 * C2 + c0);
    uint4 vc = *(const uint4*)(fb + (size_t)m2 * C2 + c0);

    float r[8];
    {
        const unsigned av[4] = {va.x, va.y, va.z, va.w};
        const unsigned bv[4] = {vb.x, vb.y, vb.z, vb.w};
        const unsigned cv[4] = {vc.x, vc.y, vc.z, vc.w};
#pragma unroll
        for (int q = 0; q < 4; ++q) {
            r[2 * q + 0] = w0 * bf2f((unsigned short)(av[q] & 0xffff))
                         + w1 * bf2f((unsigned short)(bv[q] & 0xffff))
                         + w2 * bf2f((unsigned short)(cv[q] & 0xffff));
            r[2 * q + 1] = w0 * bf2f((unsigned short)(av[q] >> 16))
                         + w1 * bf2f((unsigned short)(bv[q] >> 16))
                         + w2 * bf2f((unsigned short)(cv[q] >> 16));
        }
    }
    uint4 outv;
    outv.x = (unsigned)f2bf(r[0]) | ((unsigned)f2bf(r[1]) << 16);
    outv.y = (unsigned)f2bf(r[2]) | ((unsigned)f2bf(r[3]) << 16);
    outv.z = (unsigned)f2bf(r[4]) | ((unsigned)f2bf(r[5]) << 16);
    outv.w = (unsigned)f2bf(r[6]) | ((unsigned)f2bf(r[7]) << 16);
    *(uint4*)(xT + pt * K1 + C1 + c0) = outv;
}

// ======= k_stats: gemm1 compute-only pass for BN1 Σh1 / Σh1² per channel ====
#define S_TK 64
__launch_bounds__(256)
__global__ void k_stats(const unsigned short* __restrict__ xT,
                        const unsigned short* __restrict__ W1b,
                        float* __restrict__ sum1, float* __restrict__ ssq1) {
    __shared__ unsigned short As[128 * S_TK];
    __shared__ unsigned short Bs[128 * S_TK];
    __shared__ float s_sum[128], s_ssq[128];
    const int t = threadIdx.x;
    const int lane = t & 63, w = t >> 6;
    const int wm = w >> 1, wc = w & 1;
    const long rbase = (long)blockIdx.x * 128;
    const int cb = blockIdx.y * 128;

    if (t < 128) { s_sum[t] = 0.f; s_ssq[t] = 0.f; }

    v4f acc[4][4];
#pragma unroll
    for (int r = 0; r < 4; ++r)
#pragma unroll
        for (int c = 0; c < 4; ++c) acc[r][c] = (v4f)(0.f);

    const int srow = w * 32 + (lane >> 3);
    const int sch = (lane & 7) * 8;
    const unsigned short* Ag = xT + (rbase + srow) * K1 + sch;
    const unsigned short* Bg = W1b + (size_t)(cb + srow) * K1 + sch;

    for (int k0 = 0; k0 < K1; k0 += S_TK) {
#pragma unroll
        for (int j = 0; j < 4; ++j) {
            gload16(Ag + (size_t)(j * 8) * K1 + k0, As + (w * 32 + j * 8) * S_TK);
            gload16(Bg + (size_t)(j * 8) * K1 + k0, Bs + (w * 32 + j * 8) * S_TK);
        }
        __syncthreads();
        const unsigned short* ApL = As + (wm * 64 + (lane & 15)) * S_TK + (lane >> 4) * 8;
        const unsigned short* BpL = Bs + (wc * 64 + (lane & 15)) * S_TK + (lane >> 4) * 8;
#pragma unroll
        for (int ks = 0; ks < 2; ++ks) {
            v8s af[4], bg[4];
#pragma unroll
            for (int r = 0; r < 4; ++r) af[r] = *(const v8s*)(ApL + r * 16 * S_TK + ks * 32);
#pragma unroll
            for (int c = 0; c < 4; ++c) bg[c] = *(const v8s*)(BpL + c * 16 * S_TK + ks * 32);
#pragma unroll
            for (int r = 0; r < 4; ++r)
#pragma unroll
                for (int c = 0; c < 4; ++c)
                    acc[r][c] = __builtin_amdgcn_mfma_f32_16x16x32_bf16(af[r], bg[c], acc[r][c], 0, 0, 0);
        }
        __syncthreads();
    }

    const int q = lane >> 4, ln = lane & 15;
#pragma unroll
    for (int c = 0; c < 4; ++c) {
        int col = wc * 64 + c * 16 + ln;
        float s = 0.f, sq = 0.f;
#pragma unroll
        for (int r = 0; r < 4; ++r)
#pragma unroll
            for (int i = 0; i < 4; ++i) {
                float v = acc[r][c][i];
                s += v; sq += v * v;
            }
        s += __shfl_xor(s, 16); s += __shfl_xor(s, 32);
        sq += __shfl_xor(sq, 16); sq += __shfl_xor(sq, 32);
        if (q == 0) {
            atomicAdd(&s_sum[col], s);
            atomicAdd(&s_ssq[col], sq);
        }
    }
    __syncthreads();
    if (t < 128) {
        atomicAdd(&sum1[cb + t], s_sum[t]);
        atomicAdd(&ssq1[cb + t], s_ssq[t]);
    }
}

// ======= k_fused: per 64-row tile — gemm1 -> BN1+ReLU (LDS) -> gemm2 ========
// h2 written row-major [globalM, 256]; BN2 stats accumulated.
__launch_bounds__(256)
__global__ void k_fused(const unsigned short* __restrict__ xT,
                        const unsigned short* __restrict__ W1b,
                        const unsigned short* __restrict__ W2b,
                        const float* __restrict__ sum1, const float* __restrict__ ssq1,
                        const float* __restrict__ g1, const float* __restrict__ b1,
                        unsigned short* __restrict__ h2,
                        float* __restrict__ sum2, float* __restrict__ ssq2) {
    __shared__ unsigned short smAB[64 * 64 + 256 * 64];  // As(8KB) | Bs(32KB); reused as 64x256 out tile
    __shared__ unsigned short Ys[64 * 256];              // y tile, chunk-swizzled (32KB)
    __shared__ float sc1[CO], sh1[CO], s_sum[CO], s_ssq[CO];
    unsigned short* As = smAB;
    unsigned short* Bs = smAB + 64 * 64;

    const int t = threadIdx.x;
    const int lane = t & 63, w = t >> 6;
    const int q = lane >> 4, ln = lane & 15;
    const long rbm = (long)blockIdx.x * 64;

    // fold BN1 finalize per-block (stream-ordered after k_stats)
    {
        const float invn = 1.f / (float)MTOT;
        float m = sum1[t] * invn;
        float v = ssq1[t] * invn - m * m;
        float s = g1[t] * rsqrtf(v + 1e-5f);
        sc1[t] = s;
        sh1[t] = b1[t] - m * s;
        s_sum[t] = 0.f; s_ssq[t] = 0.f;
    }
    __syncthreads();

    v4f acc[4][4];
#pragma unroll
    for (int r = 0; r < 4; ++r)
#pragma unroll
        for (int c = 0; c < 4; ++c) acc[r][c] = (v4f)(0.f);

    const int sr8 = lane >> 3, sc8 = (lane & 7) * 8;

    // -------- phase A: h1 tile = xT[rbm:rbm+64] @ W1^T (all 256 cols) -------
    for (int k0 = 0; k0 < K1; k0 += 64) {
#pragma unroll
        for (int j = 0; j < 2; ++j)
            gload16(xT + (size_t)(rbm + w * 16 + j * 8 + sr8) * K1 + k0 + sc8,
                    As + (w * 16 + j * 8) * 64);
#pragma unroll
        for (int j = 0; j < 8; ++j)
            gload16(W1b + (size_t)(w * 64 + j * 8 + sr8) * K1 + k0 + sc8,
                    Bs + (w * 64 + j * 8) * 64);
        __syncthreads();
        const unsigned short* ApL = As + ln * 64 + q * 8;
        const unsigned short* BpL = Bs + (w * 64 + ln) * 64 + q * 8;
#pragma unroll
        for (int ks = 0; ks < 2; ++ks) {
            v8s af[4], bg[4];
#pragma unroll
            for (int r = 0; r < 4; ++r) af[r] = *(const v8s*)(ApL + r * 16 * 64 + ks * 32);
#pragma unroll
            for (int c = 0; c < 4; ++c) bg[c] = *(const v8s*)(BpL + c * 16 * 64 + ks * 32);
#pragma unroll
            for (int r = 0; r < 4; ++r)
#pragma unroll
                for (int c = 0; c < 4; ++c)
                    acc[r][c] = __builtin_amdgcn_mfma_f32_16x16x32_bf16(af[r], bg[c], acc[r][c], 0, 0, 0);
        }
        __syncthreads();
    }

    // -------- phase B: y = relu(bn1(h1)) -> Ys (swizzled row-major [64][256]) ----
#pragma unroll
    for (int c = 0; c < 4; ++c) {
        int col = w * 64 + c * 16 + ln;
        float sv = sc1[col], hv = sh1[col];
        int kc = col >> 3, ci = col & 7;
#pragma unroll
        for (int r = 0; r < 4; ++r)
#pragma unroll
            for (int i = 0; i < 4; ++i) {
                int row = r * 16 + q * 4 + i;
                float y = fmaxf(acc[r][c][i] * sv + hv, 0.f);
                Ys[row * 256 + 8 * (kc ^ (row & 15)) + ci] = f2bf(y);
            }
    }
    __syncthreads();

    // -------- phase C: out tile = y @ W2^T (K=256, A entirely in LDS) -------
#pragma unroll
    for (int r = 0; r < 4; ++r)
#pragma unroll
        for (int c = 0; c < 4; ++c) acc[r][c] = (v4f)(0.f);

    for (int k0 = 0; k0 < CO; k0 += 64) {
#pragma unroll
        for (int j = 0; j < 8; ++j)
            gload16(W2b + (size_t)(w * 64 + j * 8 + sr8) * CO + k0 + sc8,
                    Bs + (w * 64 + j * 8) * 64);
        __syncthreads();
        const unsigned short* BpL = Bs + (w * 64 + ln) * 64 + q * 8;
#pragma unroll
        for (int ks = 0; ks < 2; ++ks) {
            v8s af[4], bg[4];
            int kc2 = (k0 >> 3) + ks * 4 + q;
#pragma unroll
            for (int r = 0; r < 4; ++r)
                af[r] = *(const v8s*)&Ys[(r * 16 + ln) * 256 + 8 * (kc2 ^ ln)];
#pragma unroll
            for (int c = 0; c < 4; ++c) bg[c] = *(const v8s*)(BpL + c * 16 * 64 + ks * 32);
#pragma unroll
            for (int r = 0; r < 4; ++r)
#pragma unroll
                for (int c = 0; c < 4; ++c)
                    acc[r][c] = __builtin_amdgcn_mfma_f32_16x16x32_bf16(af[r], bg[c], acc[r][c], 0, 0, 0);
        }
        __syncthreads();
    }

    // -------- phase D: BN2 stats + swizzled tile -> coalesced h2 stores -----
#pragma unroll
    for (int c = 0; c < 4; ++c) {
        int col = w * 64 + c * 16 + ln;
        int cc = col >> 3, ci = col & 7;
        float s = 0.f, sq = 0.f;
#pragma unroll
        for (int r = 0; r < 4; ++r)
#pragma unroll
            for (int i = 0; i < 4; ++i) {
                int row = r * 16 + q * 4 + i;
                float v = acc[r][c][i];
                smAB[row * 256 + 8 * (cc ^ (row & 15)) + ci] = f2bf(v);
                s += v; sq += v * v;
            }
        s += __shfl_xor(s, 16); s += __shfl_xor(s, 32);
        sq += __shfl_xor(sq, 16); sq += __shfl_xor(sq, 32);
        if (q == 0) {
            atomicAdd(&s_sum[col], s);
            atomicAdd(&s_ssq[col], sq);
        }
    }
    __syncthreads();
    {
        int row2 = t >> 5, cc2 = t & 31;
#pragma unroll
        for (int j = 0; j < 8; ++j) {
            int row = row2 + 8 * j;
            uint4 v = *(const uint4*)&smAB[row * 256 + 8 * (cc2 ^ (row & 15))];
            *(uint4*)&h2[(size_t)(rbm + row) * CO + cc2 * 8] = v;
        }
    }
    atomicAdd(&sum2[t], s_sum[t]);
    atomicAdd(&ssq2[t], s_ssq[t]);
}

// -------- k_apply: BN2+ReLU + transpose [B,N,CO] -> out [B,CO,N] fp32 -------
__global__ void k_apply(const unsigned short* __restrict__ h2,
                        const float* __restrict__ sum2, const float* __restrict__ ssq2,
                        const float* __restrict__ g2, const float* __restrict__ b2,
                        float* __restrict__ out) {
    __shared__ float T[64][36];
    __shared__ float sc[64], sh[64];
    int b = blockIdx.z;
    int cb = blockIdx.y * 64;
    int n0 = blockIdx.x * 32;
    int t = threadIdx.x;
    if (t < 64) {
        const float invn = 1.f / (float)MTOT;
        int o = cb + t;
        float m = sum2[o] * invn;
        float v = ssq2[o] * invn - m * m;
        float s = g2[o] * rsqrtf(v + 1e-5f);
        sc[t] = s;
        sh[t] = b2[o] - m * s;
    }
    __syncthreads();
    {
        int nl = t >> 3, oc = (t & 7) * 8;
        uint4 hv = *(const uint4*)&h2[((size_t)b * NN + n0 + nl) * CO + cb + oc];
        const unsigned uv[4] = {hv.x, hv.y, hv.z, hv.w};
#pragma unroll
        for (int k = 0; k < 4; ++k) {
            int ch0 = oc + 2 * k;
            T[ch0 + 0][nl] = fmaxf(bf2f((unsigned short)(uv[k] & 0xffff)) * sc[ch0] + sh[ch0], 0.f);
            T[ch0 + 1][nl] = fmaxf(bf2f((unsigned short)(uv[k] >> 16)) * sc[ch0 + 1] + sh[ch0 + 1], 0.f);
        }
    }
    __syncthreads();
    {
        int o = t >> 2, jb = t & 3;
#pragma unroll
        for (int j2 = 0; j2 < 2; ++j2) {
            int j = jb + j2 * 4;
            float4 v = *(const float4*)&T[o][j * 4];
            *(float4*)&out[((size_t)(b * CO + cb + o)) * NN + n0 + j * 4] = v;
        }
    }
}

extern "C" void kernel_launch(void* const* d_in, const int* in_sizes, int n_in,
                              void* d_out, int out_size, void* d_ws, size_t ws_size,
                              hipStream_t stream) {
    const float* p1 = (const float*)d_in[0];
    const float* p2 = (const float*)d_in[1];
    const float* f1 = (const float*)d_in[2];
    const float* f2 = (const float*)d_in[3];
    const void*  idx = d_in[4];
    const float* W1 = (const float*)d_in[5];
    const float* g1 = (const float*)d_in[6];
    const float* b1 = (const float*)d_in[7];
    const float* W2 = (const float*)d_in[8];
    const float* g2 = (const float*)d_in[9];
    const float* b2 = (const float*)d_in[10];
    float* out = (float*)d_out;

    char* ws = (char*)d_ws;
    float* stats = (float*)(ws + STATS_OFF);
    float* sum1 = stats + 0;     float* ssq1 = stats + 256;
    float* sum2 = stats + 1024;  float* ssq2 = stats + 1280;
    int* flag64 = (int*)(ws + FLAG_OFF);
    unsigned short* W1b = (unsigned short*)(ws + W1B_OFF);
    unsigned short* W2b = (unsigned short*)(ws + W2B_OFF);
    unsigned short* f2t = (unsigned short*)(ws + F2T_OFF);
    unsigned short* xT  = (unsigned short*)(ws + XT_OFF);
    unsigned short* h2  = (unsigned short*)(ws + H2_OFF);

    k_prep<<<577, 256, 0, stream>>>(idx, flag64, stats, W1, W1b, W2, W2b);
    k_tr_f2<<<dim3(MM / 32, C2 / 64, BB), 256, 0, stream>>>(f2, f2t);
    k_tr_f1<<<dim3(NN / 32, 1, BB), 256, 0, stream>>>(f1, xT);
    k_interp<<<MTOT / 8, 256, 0, stream>>>(p1, p2, idx, flag64, f2t, xT);
    k_stats<<<dim3(MTOT / 128, 2), 256, 0, stream>>>(xT, W1b, sum1, ssq1);
    k_fused<<<MTOT / 64, 256, 0, stream>>>(xT, W1b, W2b, sum1, ssq1, g1, b1, h2, sum2, ssq2);
    k_apply<<<dim3(NN / 32, CO / 64, BB), 256, 0, stream>>>(h2, sum2, ssq2, g2, b2, out);
}